// Round 8
// baseline (1082.660 us; speedup 1.0000x reference)
//
#include <hip/hip_runtime.h>
#include <hip/hip_bf16.h>

#define NFEAT 128
#define NHID  64
#define NCLASS 40
#define NLAYERS 4

// fp32 -> bf16 bits, round-to-nearest-even
static __device__ __forceinline__ unsigned short f2bf(float f) {
    unsigned u = __float_as_uint(f);
    unsigned r = (u + 0x7FFF + ((u >> 16) & 1)) >> 16;
    return (unsigned short)r;
}
static __device__ __forceinline__ float bf2f(unsigned short h) {
    return __uint_as_float((unsigned)h << 16);
}

// ---------------- CSR build ----------------

// pass 1: rank via returning atomic ONLY (1 atomic/edge)
__global__ __launch_bounds__(256) void count_rank_k(const int* __restrict__ ei, int E,
                             int* __restrict__ cnt_col, int* __restrict__ rank) {
    int t = blockIdx.x * blockDim.x + threadIdx.x;
    int base = t * 4;
    if (base >= E) return;
    if (base + 4 <= E) {
        int4 c4 = *reinterpret_cast<const int4*>(ei + E + base);
        int4 k4;
        k4.x = atomicAdd(&cnt_col[c4.x], 1);
        k4.y = atomicAdd(&cnt_col[c4.y], 1);
        k4.z = atomicAdd(&cnt_col[c4.z], 1);
        k4.w = atomicAdd(&cnt_col[c4.w], 1);
        *reinterpret_cast<int4*>(rank + base) = k4;
    } else {
        for (int e = base; e < E; ++e)
            rank[e] = atomicAdd(&cnt_col[ei[E + e]], 1);
    }
}

// block-level exclusive scan (1024 elems / block), emits block sums; fused dinv
__global__ __launch_bounds__(1024) void scanA_k(const int* __restrict__ cnt, int* __restrict__ off,
                        int* __restrict__ bsum, float* __restrict__ dinv, int n) {
    __shared__ int t[1024];
    int i = blockIdx.x * 1024 + threadIdx.x;
    int x = (i < n) ? cnt[i] : 0;
    if (i < n) dinv[i] = 1.0f / sqrtf((float)(x + 1));   // deg incl. self loop
    t[threadIdx.x] = x;
    __syncthreads();
    for (int d = 1; d < 1024; d <<= 1) {
        int y = (threadIdx.x >= (unsigned)d) ? t[threadIdx.x - d] : 0;
        __syncthreads();
        t[threadIdx.x] += y;
        __syncthreads();
    }
    if (i < n) off[i] = t[threadIdx.x] - x;   // exclusive
    if (threadIdx.x == 1023) bsum[blockIdx.x] = t[1023];
}

__global__ __launch_bounds__(1024) void scanB_k(int* __restrict__ bsum, int nb) {
    __shared__ int t[1024];
    int x = (threadIdx.x < (unsigned)nb) ? bsum[threadIdx.x] : 0;
    t[threadIdx.x] = x;
    __syncthreads();
    for (int d = 1; d < 1024; d <<= 1) {
        int y = (threadIdx.x >= (unsigned)d) ? t[threadIdx.x - d] : 0;
        __syncthreads();
        t[threadIdx.x] += y;
        __syncthreads();
    }
    if (threadIdx.x < (unsigned)nb) bsum[threadIdx.x] = t[threadIdx.x] - x;
}

// finalize offsets; fused gs zero-init
__global__ __launch_bounds__(1024) void scanC_k(int* __restrict__ off, const int* __restrict__ bsum,
                        float* __restrict__ gs, int n, int total) {
    int i = blockIdx.x * 1024 + threadIdx.x;
    if (i < n) {
        off[i] += bsum[blockIdx.x];
        gs[i] = 0.f;
    }
    if (i == 0) off[n] = total;
}

// pass 2: atomic-free slot scatter + out-degree forget-atomics (overlap with stores)
__global__ __launch_bounds__(256) void scatter_k(const int* __restrict__ ei, int E,
                          const int* __restrict__ col_off, const int* __restrict__ rank,
                          int* __restrict__ cnt_row, int* __restrict__ csr) {
    int t = blockIdx.x * blockDim.x + threadIdx.x;
    int base = t * 8;
    if (base >= E) return;
    if (base + 8 <= E) {
        int4 rA = *reinterpret_cast<const int4*>(ei + base);
        int4 rB = *reinterpret_cast<const int4*>(ei + base + 4);
        int4 cA = *reinterpret_cast<const int4*>(ei + E + base);
        int4 cB = *reinterpret_cast<const int4*>(ei + E + base + 4);
        int4 kA = *reinterpret_cast<const int4*>(rank + base);
        int4 kB = *reinterpret_cast<const int4*>(rank + base + 4);
        atomicAdd(&cnt_row[rA.x], 1);
        atomicAdd(&cnt_row[rA.y], 1);
        atomicAdd(&cnt_row[rA.z], 1);
        atomicAdd(&cnt_row[rA.w], 1);
        atomicAdd(&cnt_row[rB.x], 1);
        atomicAdd(&cnt_row[rB.y], 1);
        atomicAdd(&cnt_row[rB.z], 1);
        atomicAdd(&cnt_row[rB.w], 1);
        csr[col_off[cA.x] + kA.x] = rA.x;
        csr[col_off[cA.y] + kA.y] = rA.y;
        csr[col_off[cA.z] + kA.z] = rA.z;
        csr[col_off[cA.w] + kA.w] = rA.w;
        csr[col_off[cB.x] + kB.x] = rB.x;
        csr[col_off[cB.y] + kB.y] = rB.y;
        csr[col_off[cB.z] + kB.z] = rB.z;
        csr[col_off[cB.w] + kB.w] = rB.w;
    } else {
        for (int e = base; e < E; ++e) {
            atomicAdd(&cnt_row[ei[e]], 1);
            csr[col_off[ei[E + e]] + rank[e]] = ei[e];
        }
    }
}

// ---------------- fused encoder + skip projection ----------------
// X = relu(x @ enc_W^T + enc_b); X16 = bf16(X); skip = X @ W_skip^T
__global__ __launch_bounds__(256) void enc_skip_k(const float* __restrict__ A,
                        const float* __restrict__ encW, const float* __restrict__ encb,
                        const float* __restrict__ Wskip,
                        float* __restrict__ X, unsigned short* __restrict__ X16,
                        float* __restrict__ skip, int n) {
    int v = blockIdx.x * blockDim.x + threadIdx.x;
    if (v >= n) return;
    const float4* ap = reinterpret_cast<const float4*>(A + (size_t)v * NFEAT);
    float4* Xp = reinterpret_cast<float4*>(X + (size_t)v * NHID);
    ushort4* Hp = reinterpret_cast<ushort4*>(X16 + (size_t)v * NHID);
    float xs[NHID];
#pragma unroll 1
    for (int mc = 0; mc < NHID; mc += 32) {
        float acc[32];
#pragma unroll
        for (int m = 0; m < 32; ++m) acc[m] = encb[mc + m];
#pragma unroll 1
        for (int kb = 0; kb < NFEAT / 4; ++kb) {
            float4 a4 = ap[kb];
#pragma unroll
            for (int m = 0; m < 32; ++m) {
                const float* wr = encW + (size_t)(mc + m) * NFEAT + kb * 4;
                acc[m] = fmaf(a4.x, wr[0], acc[m]);
                acc[m] = fmaf(a4.y, wr[1], acc[m]);
                acc[m] = fmaf(a4.z, wr[2], acc[m]);
                acc[m] = fmaf(a4.w, wr[3], acc[m]);
            }
        }
#pragma unroll
        for (int m = 0; m < 32; m += 4) {
            float4 o;
            o.x = fmaxf(acc[m + 0], 0.f);
            o.y = fmaxf(acc[m + 1], 0.f);
            o.z = fmaxf(acc[m + 2], 0.f);
            o.w = fmaxf(acc[m + 3], 0.f);
            xs[mc + m + 0] = o.x; xs[mc + m + 1] = o.y;
            xs[mc + m + 2] = o.z; xs[mc + m + 3] = o.w;
            Xp[(mc + m) >> 2] = o;
            ushort4 h;
            h.x = f2bf(o.x); h.y = f2bf(o.y); h.z = f2bf(o.z); h.w = f2bf(o.w);
            Hp[(mc + m) >> 2] = h;
        }
    }
    // skip = xs @ Wskip^T
    float4* Sp = reinterpret_cast<float4*>(skip + (size_t)v * NHID);
#pragma unroll 1
    for (int m = 0; m < NHID; m += 4) {
        float s0 = 0.f, s1 = 0.f, s2 = 0.f, s3 = 0.f;
#pragma unroll
        for (int k = 0; k < NHID; ++k) {
            float av = xs[k];
            s0 = fmaf(av, Wskip[(m + 0) * NHID + k], s0);
            s1 = fmaf(av, Wskip[(m + 1) * NHID + k], s1);
            s2 = fmaf(av, Wskip[(m + 2) * NHID + k], s2);
            s3 = fmaf(av, Wskip[(m + 3) * NHID + k], s3);
        }
        float4 o; o.x = s0; o.y = s1; o.z = s2; o.w = s3;
        Sp[m >> 2] = o;
    }
}

// ---------------- dense K=64 (decode) ----------------

template<int K, int M, bool RELU, bool BIAS>
__global__ __launch_bounds__(256) void dense_small_k(const float* __restrict__ A, const float* __restrict__ W,
                              const float* __restrict__ b, float* __restrict__ out, int n) {
    int v = blockIdx.x * blockDim.x + threadIdx.x;
    if (v >= n) return;
    float a[K];
    const float4* ap = reinterpret_cast<const float4*>(A + (size_t)v * K);
#pragma unroll
    for (int k = 0; k < K / 4; ++k) {
        float4 t = ap[k];
        a[4 * k + 0] = t.x; a[4 * k + 1] = t.y; a[4 * k + 2] = t.z; a[4 * k + 3] = t.w;
    }
    float4* op = reinterpret_cast<float4*>(out + (size_t)v * M);
#pragma unroll 1
    for (int m = 0; m < M; m += 4) {
        float acc0 = BIAS ? b[m + 0] : 0.f;
        float acc1 = BIAS ? b[m + 1] : 0.f;
        float acc2 = BIAS ? b[m + 2] : 0.f;
        float acc3 = BIAS ? b[m + 3] : 0.f;
#pragma unroll
        for (int k = 0; k < K; ++k) {
            float av = a[k];
            acc0 = fmaf(av, W[(m + 0) * K + k], acc0);
            acc1 = fmaf(av, W[(m + 1) * K + k], acc1);
            acc2 = fmaf(av, W[(m + 2) * K + k], acc2);
            acc3 = fmaf(av, W[(m + 3) * K + k], acc3);
        }
        if (RELU) {
            acc0 = fmaxf(acc0, 0.f); acc1 = fmaxf(acc1, 0.f);
            acc2 = fmaxf(acc2, 0.f); acc3 = fmaxf(acc3, 0.f);
        }
        float4 o; o.x = acc0; o.y = acc1; o.z = acc2; o.w = acc3;
        op[m >> 2] = o;
    }
}

// ---------------- fused gather on bf16 rows: 16-lane group / node, 8-deep ----------------
// pre[v] = dv*sum(dinv[s]*X[s]) + dv^2*X[v];  gs[s] += ||X[s]-X[v]||^2

#define GLOAD(i) \
    int s##i = csr[e + i]; \
    float w##i = dinv[s##i]; \
    ushort4 h##i = reinterpret_cast<const ushort4*>(X16 + (size_t)s##i * NHID)[sub];

#define GPROC(i) \
    { float fx = bf2f(h##i.x), fy = bf2f(h##i.y), fz = bf2f(h##i.z), fw = bf2f(h##i.w); \
      acc.x = fmaf(w##i, fx, acc.x); acc.y = fmaf(w##i, fy, acc.y); \
      acc.z = fmaf(w##i, fz, acc.z); acc.w = fmaf(w##i, fw, acc.w); \
      float dx = fx - xv.x; p##i = dx * dx; \
      dx = fy - xv.y; p##i = fmaf(dx, dx, p##i); \
      dx = fz - xv.z; p##i = fmaf(dx, dx, p##i); \
      dx = fw - xv.w; p##i = fmaf(dx, dx, p##i); }

__global__ __launch_bounds__(256) void gather16_k(const unsigned short* __restrict__ X16,
                          const int* __restrict__ csr,
                          const int* __restrict__ col_off, const float* __restrict__ dinv,
                          float* __restrict__ pre, float* __restrict__ gs, int n) {
    int gid = (blockIdx.x * blockDim.x + threadIdx.x) >> 4;
    int ngrp = (gridDim.x * blockDim.x) >> 4;
    int sub = threadIdx.x & 15;

    for (int v = gid; v < n; v += ngrp) {
        ushort4 hv = reinterpret_cast<const ushort4*>(X16 + (size_t)v * NHID)[sub];
        float4 xv;
        xv.x = bf2f(hv.x); xv.y = bf2f(hv.y); xv.z = bf2f(hv.z); xv.w = bf2f(hv.w);
        int beg = col_off[v], end = col_off[v + 1];
        float4 acc = make_float4(0.f, 0.f, 0.f, 0.f);
        int e = beg;
        for (; e + 8 <= end; e += 8) {
            GLOAD(0) GLOAD(1) GLOAD(2) GLOAD(3)
            GLOAD(4) GLOAD(5) GLOAD(6) GLOAD(7)
            float p0, p1, p2, p3, p4, p5, p6, p7;
            GPROC(0) GPROC(1) GPROC(2) GPROC(3)
            GPROC(4) GPROC(5) GPROC(6) GPROC(7)
#pragma unroll
            for (int m = 1; m <= 8; m <<= 1) {
                p0 += __shfl_xor(p0, m, 64);
                p1 += __shfl_xor(p1, m, 64);
                p2 += __shfl_xor(p2, m, 64);
                p3 += __shfl_xor(p3, m, 64);
                p4 += __shfl_xor(p4, m, 64);
                p5 += __shfl_xor(p5, m, 64);
                p6 += __shfl_xor(p6, m, 64);
                p7 += __shfl_xor(p7, m, 64);
            }
            if (sub == 0) {
                atomicAdd(&gs[s0], p0);
                atomicAdd(&gs[s1], p1);
                atomicAdd(&gs[s2], p2);
                atomicAdd(&gs[s3], p3);
                atomicAdd(&gs[s4], p4);
                atomicAdd(&gs[s5], p5);
                atomicAdd(&gs[s6], p6);
                atomicAdd(&gs[s7], p7);
            }
        }
        for (; e < end; ++e) {
            GLOAD(0)
            float p0;
            GPROC(0)
#pragma unroll
            for (int m = 1; m <= 8; m <<= 1) p0 += __shfl_xor(p0, m, 64);
            if (sub == 0) atomicAdd(&gs[s0], p0);
        }
        float dv = dinv[v];
        float dv2 = dv * dv;
        float4 o;
        o.x = fmaf(dv, acc.x, dv2 * xv.x);
        o.y = fmaf(dv, acc.y, dv2 * xv.y);
        o.z = fmaf(dv, acc.z, dv2 * xv.z);
        o.w = fmaf(dv, acc.w, dv2 * xv.w);
        reinterpret_cast<float4*>(pre + (size_t)v * NHID)[sub] = o;
    }
}

// ---------------- fused per-layer epilogue ----------------
// t = relu(pre @ W^T + b); g = tanh(gs/max(outdeg,1));
// X = (X + g*(t + skip)) / (1 + 2g);  X16 = bf16(X);  gs = 0 for next layer
__global__ __launch_bounds__(256) void update_k(float* __restrict__ X, unsigned short* __restrict__ X16,
                         const float* __restrict__ pre,
                         const float* __restrict__ skip, const float* __restrict__ W,
                         const float* __restrict__ b, float* __restrict__ gs,
                         const int* __restrict__ cnt_row, int n) {
    int v = blockIdx.x * blockDim.x + threadIdx.x;
    if (v >= n) return;
    float a[NHID];
    const float4* ap = reinterpret_cast<const float4*>(pre + (size_t)v * NHID);
#pragma unroll
    for (int k = 0; k < NHID / 4; ++k) {
        float4 t = ap[k];
        a[4 * k + 0] = t.x; a[4 * k + 1] = t.y; a[4 * k + 2] = t.z; a[4 * k + 3] = t.w;
    }
    float gv = tanhf(gs[v] / fmaxf((float)cnt_row[v], 1.f));
    gs[v] = 0.f;
    float inv = 1.0f / (1.0f + 2.0f * gv);

    float4* Xp = reinterpret_cast<float4*>(X + (size_t)v * NHID);
    ushort4* Hp = reinterpret_cast<ushort4*>(X16 + (size_t)v * NHID);
    const float4* Sp = reinterpret_cast<const float4*>(skip + (size_t)v * NHID);
#pragma unroll 1
    for (int m = 0; m < NHID; m += 4) {
        float t0 = b[m + 0], t1 = b[m + 1], t2 = b[m + 2], t3 = b[m + 3];
#pragma unroll
        for (int k = 0; k < NHID; ++k) {
            float av = a[k];
            t0 = fmaf(av, W[(m + 0) * NHID + k], t0);
            t1 = fmaf(av, W[(m + 1) * NHID + k], t1);
            t2 = fmaf(av, W[(m + 2) * NHID + k], t2);
            t3 = fmaf(av, W[(m + 3) * NHID + k], t3);
        }
        t0 = fmaxf(t0, 0.f); t1 = fmaxf(t1, 0.f);
        t2 = fmaxf(t2, 0.f); t3 = fmaxf(t3, 0.f);
        float4 x4 = Xp[m >> 2];
        float4 s4 = Sp[m >> 2];
        float4 o;
        o.x = (x4.x + gv * (t0 + s4.x)) * inv;
        o.y = (x4.y + gv * (t1 + s4.y)) * inv;
        o.z = (x4.z + gv * (t2 + s4.z)) * inv;
        o.w = (x4.w + gv * (t3 + s4.w)) * inv;
        Xp[m >> 2] = o;
        ushort4 h;
        h.x = f2bf(o.x); h.y = f2bf(o.y); h.z = f2bf(o.z); h.w = f2bf(o.w);
        Hp[m >> 2] = h;
    }
}

// ---------------- launch ----------------

extern "C" void kernel_launch(void* const* d_in, const int* in_sizes, int n_in,
                              void* d_out, int out_size, void* d_ws, size_t ws_size,
                              hipStream_t stream) {
    const float* x      = (const float*)d_in[0];
    const int*   ei     = (const int*)  d_in[1];
    const float* enc_W  = (const float*)d_in[2];
    const float* enc_b  = (const float*)d_in[3];
    const float* conv_W = (const float*)d_in[4];
    const float* conv_b = (const float*)d_in[5];
    const float* W_skip = (const float*)d_in[6];
    const float* dec_W  = (const float*)d_in[7];
    const float* dec_b  = (const float*)d_in[8];

    const int n = in_sizes[0] / NFEAT;
    const int E = in_sizes[1] / 2;

    char* ws = (char*)d_ws;
    auto alloc = [&](size_t bytes) {
        char* p = ws;
        ws += (bytes + 255) & ~(size_t)255;
        return p;
    };

    float* X    = (float*)alloc((size_t)n * NHID * 4);
    unsigned short* X16 = (unsigned short*)alloc((size_t)n * NHID * 2);
    float* pre  = (float*)alloc((size_t)n * NHID * 4);
    float* skip = (float*)alloc((size_t)n * NHID * 4);
    float* gs   = (float*)alloc((size_t)n * 4);
    float* dinv = (float*)alloc((size_t)n * 4);
    int* cnt_row = (int*)alloc((size_t)n * 4);
    int* cnt_col = (int*)alloc((size_t)n * 4);
    int* col_off = (int*)alloc((size_t)(n + 1) * 4);
    int* rank    = (int*)alloc((size_t)E * 4);
    int* bsc     = (int*)alloc(1024 * 4);
    int* csr     = (int*)alloc((size_t)E * 4);

    hipMemsetAsync(cnt_row, 0, (size_t)n * 4, stream);
    hipMemsetAsync(cnt_col, 0, (size_t)n * 4, stream);

    count_rank_k<<<(E / 4 + 255) / 256, 256, 0, stream>>>(ei, E, cnt_col, rank);

    int nb = (n + 1023) / 1024;
    scanA_k<<<nb, 1024, 0, stream>>>(cnt_col, col_off, bsc, dinv, n);
    scanB_k<<<1, 1024, 0, stream>>>(bsc, nb);
    scanC_k<<<nb, 1024, 0, stream>>>(col_off, bsc, gs, n, E);
    scatter_k<<<(E / 8 + 255) / 256, 256, 0, stream>>>(ei, E, col_off, rank, cnt_row, csr);

    // encoder + skip (fused): X, X16, skip
    enc_skip_k<<<(n + 255) / 256, 256, 0, stream>>>(x, enc_W, enc_b, W_skip, X, X16, skip, n);

    for (int l = 0; l < NLAYERS; ++l) {
        gather16_k<<<2048, 256, 0, stream>>>(X16, csr, col_off, dinv, pre, gs, n);
        update_k<<<(n + 255) / 256, 256, 0, stream>>>(X, X16, pre, skip, conv_W, conv_b, gs, cnt_row, n);
    }

    // decode: out = X @ dec_W^T + dec_b
    dense_small_k<NHID, NCLASS, false, true><<<(n + 255) / 256, 256, 0, stream>>>(X, dec_W, dec_b, (float*)d_out, n);
}

// Round 9
// 994.882 us; speedup vs baseline: 1.0882x; 1.0882x over previous
//
#include <hip/hip_runtime.h>
#include <hip/hip_bf16.h>

#define NFEAT 128
#define NHID  64
#define NCLASS 40
#define NLAYERS 4

// ---------------- CSR build ----------------

// pass 1: rank via returning atomic ONLY (1 atomic/edge)
__global__ __launch_bounds__(256) void count_rank_k(const int* __restrict__ ei, int E,
                             int* __restrict__ cnt_col, int* __restrict__ rank) {
    int t = blockIdx.x * blockDim.x + threadIdx.x;
    int base = t * 4;
    if (base >= E) return;
    if (base + 4 <= E) {
        int4 c4 = *reinterpret_cast<const int4*>(ei + E + base);
        int4 k4;
        k4.x = atomicAdd(&cnt_col[c4.x], 1);
        k4.y = atomicAdd(&cnt_col[c4.y], 1);
        k4.z = atomicAdd(&cnt_col[c4.z], 1);
        k4.w = atomicAdd(&cnt_col[c4.w], 1);
        *reinterpret_cast<int4*>(rank + base) = k4;
    } else {
        for (int e = base; e < E; ++e)
            rank[e] = atomicAdd(&cnt_col[ei[E + e]], 1);
    }
}

// block-level exclusive scan (1024 elems / block), emits block sums; fused dinv
__global__ __launch_bounds__(1024) void scanA_k(const int* __restrict__ cnt, int* __restrict__ off,
                        int* __restrict__ bsum, float* __restrict__ dinv, int n) {
    __shared__ int t[1024];
    int i = blockIdx.x * 1024 + threadIdx.x;
    int x = (i < n) ? cnt[i] : 0;
    if (i < n) dinv[i] = 1.0f / sqrtf((float)(x + 1));   // deg incl. self loop
    t[threadIdx.x] = x;
    __syncthreads();
    for (int d = 1; d < 1024; d <<= 1) {
        int y = (threadIdx.x >= (unsigned)d) ? t[threadIdx.x - d] : 0;
        __syncthreads();
        t[threadIdx.x] += y;
        __syncthreads();
    }
    if (i < n) off[i] = t[threadIdx.x] - x;   // exclusive
    if (threadIdx.x == 1023) bsum[blockIdx.x] = t[1023];
}

__global__ __launch_bounds__(1024) void scanB_k(int* __restrict__ bsum, int nb) {
    __shared__ int t[1024];
    int x = (threadIdx.x < (unsigned)nb) ? bsum[threadIdx.x] : 0;
    t[threadIdx.x] = x;
    __syncthreads();
    for (int d = 1; d < 1024; d <<= 1) {
        int y = (threadIdx.x >= (unsigned)d) ? t[threadIdx.x - d] : 0;
        __syncthreads();
        t[threadIdx.x] += y;
        __syncthreads();
    }
    if (threadIdx.x < (unsigned)nb) bsum[threadIdx.x] = t[threadIdx.x] - x;
}

// finalize offsets; fused gs zero-init
__global__ __launch_bounds__(1024) void scanC_k(int* __restrict__ off, const int* __restrict__ bsum,
                        float* __restrict__ gs, int n, int total) {
    int i = blockIdx.x * 1024 + threadIdx.x;
    if (i < n) {
        off[i] += bsum[blockIdx.x];
        gs[i] = 0.f;
    }
    if (i == 0) off[n] = total;
}

// pass 2: atomic-free slot scatter + out-degree forget-atomics (overlap with stores)
__global__ __launch_bounds__(256) void scatter_k(const int* __restrict__ ei, int E,
                          const int* __restrict__ col_off, const int* __restrict__ rank,
                          int* __restrict__ cnt_row, int* __restrict__ csr) {
    int t = blockIdx.x * blockDim.x + threadIdx.x;
    int base = t * 8;
    if (base >= E) return;
    if (base + 8 <= E) {
        int4 rA = *reinterpret_cast<const int4*>(ei + base);
        int4 rB = *reinterpret_cast<const int4*>(ei + base + 4);
        int4 cA = *reinterpret_cast<const int4*>(ei + E + base);
        int4 cB = *reinterpret_cast<const int4*>(ei + E + base + 4);
        int4 kA = *reinterpret_cast<const int4*>(rank + base);
        int4 kB = *reinterpret_cast<const int4*>(rank + base + 4);
        atomicAdd(&cnt_row[rA.x], 1);
        atomicAdd(&cnt_row[rA.y], 1);
        atomicAdd(&cnt_row[rA.z], 1);
        atomicAdd(&cnt_row[rA.w], 1);
        atomicAdd(&cnt_row[rB.x], 1);
        atomicAdd(&cnt_row[rB.y], 1);
        atomicAdd(&cnt_row[rB.z], 1);
        atomicAdd(&cnt_row[rB.w], 1);
        csr[col_off[cA.x] + kA.x] = rA.x;
        csr[col_off[cA.y] + kA.y] = rA.y;
        csr[col_off[cA.z] + kA.z] = rA.z;
        csr[col_off[cA.w] + kA.w] = rA.w;
        csr[col_off[cB.x] + kB.x] = rB.x;
        csr[col_off[cB.y] + kB.y] = rB.y;
        csr[col_off[cB.z] + kB.z] = rB.z;
        csr[col_off[cB.w] + kB.w] = rB.w;
    } else {
        for (int e = base; e < E; ++e) {
            atomicAdd(&cnt_row[ei[e]], 1);
            csr[col_off[ei[E + e]] + rank[e]] = ei[e];
        }
    }
}

// ---------------- fused encoder + skip projection ----------------
// X = relu(x @ enc_W^T + enc_b); skip = X @ W_skip^T
// waves_per_eu=2 -> VGPR cap 256: xs[64]+acc[32] stays in registers
__global__ __launch_bounds__(256, 2) void enc_skip_k(const float* __restrict__ A,
                        const float* __restrict__ encW, const float* __restrict__ encb,
                        const float* __restrict__ Wskip,
                        float* __restrict__ X, float* __restrict__ skip, int n) {
    int v = blockIdx.x * blockDim.x + threadIdx.x;
    if (v >= n) return;
    const float4* ap = reinterpret_cast<const float4*>(A + (size_t)v * NFEAT);
    float4* Xp = reinterpret_cast<float4*>(X + (size_t)v * NHID);
    float xs[NHID];
#pragma unroll 1
    for (int mc = 0; mc < NHID; mc += 32) {
        float acc[32];
#pragma unroll
        for (int m = 0; m < 32; ++m) acc[m] = encb[mc + m];
#pragma unroll 1
        for (int kb = 0; kb < NFEAT / 4; ++kb) {
            float4 a4 = ap[kb];
#pragma unroll
            for (int m = 0; m < 32; ++m) {
                const float* wr = encW + (size_t)(mc + m) * NFEAT + kb * 4;
                acc[m] = fmaf(a4.x, wr[0], acc[m]);
                acc[m] = fmaf(a4.y, wr[1], acc[m]);
                acc[m] = fmaf(a4.z, wr[2], acc[m]);
                acc[m] = fmaf(a4.w, wr[3], acc[m]);
            }
        }
#pragma unroll
        for (int m = 0; m < 32; m += 4) {
            float4 o;
            o.x = fmaxf(acc[m + 0], 0.f);
            o.y = fmaxf(acc[m + 1], 0.f);
            o.z = fmaxf(acc[m + 2], 0.f);
            o.w = fmaxf(acc[m + 3], 0.f);
            xs[mc + m + 0] = o.x; xs[mc + m + 1] = o.y;
            xs[mc + m + 2] = o.z; xs[mc + m + 3] = o.w;
            Xp[(mc + m) >> 2] = o;
        }
    }
    // skip = xs @ Wskip^T
    float4* Sp = reinterpret_cast<float4*>(skip + (size_t)v * NHID);
#pragma unroll 1
    for (int m = 0; m < NHID; m += 4) {
        float s0 = 0.f, s1 = 0.f, s2 = 0.f, s3 = 0.f;
#pragma unroll
        for (int k = 0; k < NHID; ++k) {
            float av = xs[k];
            s0 = fmaf(av, Wskip[(m + 0) * NHID + k], s0);
            s1 = fmaf(av, Wskip[(m + 1) * NHID + k], s1);
            s2 = fmaf(av, Wskip[(m + 2) * NHID + k], s2);
            s3 = fmaf(av, Wskip[(m + 3) * NHID + k], s3);
        }
        float4 o; o.x = s0; o.y = s1; o.z = s2; o.w = s3;
        Sp[m >> 2] = o;
    }
}

// ---------------- dense K=64 (decode): waves_per_eu=4 -> VGPR cap 128 ----------------

template<int K, int M, bool RELU, bool BIAS>
__global__ __launch_bounds__(256, 4) void dense_small_k(const float* __restrict__ A, const float* __restrict__ W,
                              const float* __restrict__ b, float* __restrict__ out, int n) {
    int v = blockIdx.x * blockDim.x + threadIdx.x;
    if (v >= n) return;
    float a[K];
    const float4* ap = reinterpret_cast<const float4*>(A + (size_t)v * K);
#pragma unroll
    for (int k = 0; k < K / 4; ++k) {
        float4 t = ap[k];
        a[4 * k + 0] = t.x; a[4 * k + 1] = t.y; a[4 * k + 2] = t.z; a[4 * k + 3] = t.w;
    }
    float4* op = reinterpret_cast<float4*>(out + (size_t)v * M);
#pragma unroll 1
    for (int m = 0; m < M; m += 4) {
        float acc0 = BIAS ? b[m + 0] : 0.f;
        float acc1 = BIAS ? b[m + 1] : 0.f;
        float acc2 = BIAS ? b[m + 2] : 0.f;
        float acc3 = BIAS ? b[m + 3] : 0.f;
#pragma unroll
        for (int k = 0; k < K; ++k) {
            float av = a[k];
            acc0 = fmaf(av, W[(m + 0) * K + k], acc0);
            acc1 = fmaf(av, W[(m + 1) * K + k], acc1);
            acc2 = fmaf(av, W[(m + 2) * K + k], acc2);
            acc3 = fmaf(av, W[(m + 3) * K + k], acc3);
        }
        if (RELU) {
            acc0 = fmaxf(acc0, 0.f); acc1 = fmaxf(acc1, 0.f);
            acc2 = fmaxf(acc2, 0.f); acc3 = fmaxf(acc3, 0.f);
        }
        float4 o; o.x = acc0; o.y = acc1; o.z = acc2; o.w = acc3;
        op[m >> 2] = o;
    }
}

// ---------------- fused gather (fp32): 16-lane group / node, grid-stride, 8-deep ----------------
// pre[v] = dv*sum(dinv[s]*X[s]) + dv^2*X[v];  gs[s] += ||X[s]-X[v]||^2

#define GLOAD(i) \
    int s##i = csr[e + i]; \
    float w##i = dinv[s##i]; \
    float4 x##i = reinterpret_cast<const float4*>(X + (size_t)s##i * NHID)[sub];

#define GPROC(i) \
    { acc.x = fmaf(w##i, x##i.x, acc.x); acc.y = fmaf(w##i, x##i.y, acc.y); \
      acc.z = fmaf(w##i, x##i.z, acc.z); acc.w = fmaf(w##i, x##i.w, acc.w); \
      float dx = x##i.x - xv.x; p##i = dx * dx; \
      dx = x##i.y - xv.y; p##i = fmaf(dx, dx, p##i); \
      dx = x##i.z - xv.z; p##i = fmaf(dx, dx, p##i); \
      dx = x##i.w - xv.w; p##i = fmaf(dx, dx, p##i); }

__global__ __launch_bounds__(256, 4) void gather16_k(const float* __restrict__ X,
                          const int* __restrict__ csr,
                          const int* __restrict__ col_off, const float* __restrict__ dinv,
                          float* __restrict__ pre, float* __restrict__ gs, int n) {
    int gid = (blockIdx.x * blockDim.x + threadIdx.x) >> 4;
    int ngrp = (gridDim.x * blockDim.x) >> 4;
    int sub = threadIdx.x & 15;

    for (int v = gid; v < n; v += ngrp) {
        float4 xv = reinterpret_cast<const float4*>(X + (size_t)v * NHID)[sub];
        int beg = col_off[v], end = col_off[v + 1];
        float4 acc = make_float4(0.f, 0.f, 0.f, 0.f);
        int e = beg;
        for (; e + 8 <= end; e += 8) {
            GLOAD(0) GLOAD(1) GLOAD(2) GLOAD(3)
            GLOAD(4) GLOAD(5) GLOAD(6) GLOAD(7)
            float p0, p1, p2, p3, p4, p5, p6, p7;
            GPROC(0) GPROC(1) GPROC(2) GPROC(3)
            GPROC(4) GPROC(5) GPROC(6) GPROC(7)
#pragma unroll
            for (int m = 1; m <= 8; m <<= 1) {
                p0 += __shfl_xor(p0, m, 64);
                p1 += __shfl_xor(p1, m, 64);
                p2 += __shfl_xor(p2, m, 64);
                p3 += __shfl_xor(p3, m, 64);
                p4 += __shfl_xor(p4, m, 64);
                p5 += __shfl_xor(p5, m, 64);
                p6 += __shfl_xor(p6, m, 64);
                p7 += __shfl_xor(p7, m, 64);
            }
            if (sub == 0) {
                atomicAdd(&gs[s0], p0);
                atomicAdd(&gs[s1], p1);
                atomicAdd(&gs[s2], p2);
                atomicAdd(&gs[s3], p3);
                atomicAdd(&gs[s4], p4);
                atomicAdd(&gs[s5], p5);
                atomicAdd(&gs[s6], p6);
                atomicAdd(&gs[s7], p7);
            }
        }
        for (; e < end; ++e) {
            GLOAD(0)
            float p0;
            GPROC(0)
#pragma unroll
            for (int m = 1; m <= 8; m <<= 1) p0 += __shfl_xor(p0, m, 64);
            if (sub == 0) atomicAdd(&gs[s0], p0);
        }
        float dv = dinv[v];
        float dv2 = dv * dv;
        float4 o;
        o.x = fmaf(dv, acc.x, dv2 * xv.x);
        o.y = fmaf(dv, acc.y, dv2 * xv.y);
        o.z = fmaf(dv, acc.z, dv2 * xv.z);
        o.w = fmaf(dv, acc.w, dv2 * xv.w);
        reinterpret_cast<float4*>(pre + (size_t)v * NHID)[sub] = o;
    }
}

// ---------------- fused per-layer epilogue: waves_per_eu=4 -> VGPR cap 128 ----------------
// t = relu(pre @ W^T + b); g = tanh(gs/max(outdeg,1));
// X = (X + g*(t + skip)) / (1 + 2g);  gs = 0 for next layer
__global__ __launch_bounds__(256, 4) void update_k(float* __restrict__ X, const float* __restrict__ pre,
                         const float* __restrict__ skip, const float* __restrict__ W,
                         const float* __restrict__ b, float* __restrict__ gs,
                         const int* __restrict__ cnt_row, int n) {
    int v = blockIdx.x * blockDim.x + threadIdx.x;
    if (v >= n) return;
    float a[NHID];
    const float4* ap = reinterpret_cast<const float4*>(pre + (size_t)v * NHID);
#pragma unroll
    for (int k = 0; k < NHID / 4; ++k) {
        float4 t = ap[k];
        a[4 * k + 0] = t.x; a[4 * k + 1] = t.y; a[4 * k + 2] = t.z; a[4 * k + 3] = t.w;
    }
    float gv = tanhf(gs[v] / fmaxf((float)cnt_row[v], 1.f));
    gs[v] = 0.f;
    float inv = 1.0f / (1.0f + 2.0f * gv);

    float4* Xp = reinterpret_cast<float4*>(X + (size_t)v * NHID);
    const float4* Sp = reinterpret_cast<const float4*>(skip + (size_t)v * NHID);
#pragma unroll 1
    for (int m = 0; m < NHID; m += 4) {
        float t0 = b[m + 0], t1 = b[m + 1], t2 = b[m + 2], t3 = b[m + 3];
#pragma unroll
        for (int k = 0; k < NHID; ++k) {
            float av = a[k];
            t0 = fmaf(av, W[(m + 0) * NHID + k], t0);
            t1 = fmaf(av, W[(m + 1) * NHID + k], t1);
            t2 = fmaf(av, W[(m + 2) * NHID + k], t2);
            t3 = fmaf(av, W[(m + 3) * NHID + k], t3);
        }
        t0 = fmaxf(t0, 0.f); t1 = fmaxf(t1, 0.f);
        t2 = fmaxf(t2, 0.f); t3 = fmaxf(t3, 0.f);
        float4 x4 = Xp[m >> 2];
        float4 s4 = Sp[m >> 2];
        float4 o;
        o.x = (x4.x + gv * (t0 + s4.x)) * inv;
        o.y = (x4.y + gv * (t1 + s4.y)) * inv;
        o.z = (x4.z + gv * (t2 + s4.z)) * inv;
        o.w = (x4.w + gv * (t3 + s4.w)) * inv;
        Xp[m >> 2] = o;
    }
}

// ---------------- launch ----------------

extern "C" void kernel_launch(void* const* d_in, const int* in_sizes, int n_in,
                              void* d_out, int out_size, void* d_ws, size_t ws_size,
                              hipStream_t stream) {
    const float* x      = (const float*)d_in[0];
    const int*   ei     = (const int*)  d_in[1];
    const float* enc_W  = (const float*)d_in[2];
    const float* enc_b  = (const float*)d_in[3];
    const float* conv_W = (const float*)d_in[4];
    const float* conv_b = (const float*)d_in[5];
    const float* W_skip = (const float*)d_in[6];
    const float* dec_W  = (const float*)d_in[7];
    const float* dec_b  = (const float*)d_in[8];

    const int n = in_sizes[0] / NFEAT;
    const int E = in_sizes[1] / 2;

    char* ws = (char*)d_ws;
    auto alloc = [&](size_t bytes) {
        char* p = ws;
        ws += (bytes + 255) & ~(size_t)255;
        return p;
    };

    float* X    = (float*)alloc((size_t)n * NHID * 4);
    float* pre  = (float*)alloc((size_t)n * NHID * 4);
    float* skip = (float*)alloc((size_t)n * NHID * 4);
    float* gs   = (float*)alloc((size_t)n * 4);
    float* dinv = (float*)alloc((size_t)n * 4);
    int* cnt_row = (int*)alloc((size_t)n * 4);
    int* cnt_col = (int*)alloc((size_t)n * 4);
    int* col_off = (int*)alloc((size_t)(n + 1) * 4);
    int* rank    = (int*)alloc((size_t)E * 4);
    int* bsc     = (int*)alloc(1024 * 4);
    int* csr     = (int*)alloc((size_t)E * 4);

    hipMemsetAsync(cnt_row, 0, (size_t)n * 4, stream);
    hipMemsetAsync(cnt_col, 0, (size_t)n * 4, stream);

    count_rank_k<<<(E / 4 + 255) / 256, 256, 0, stream>>>(ei, E, cnt_col, rank);

    int nb = (n + 1023) / 1024;
    scanA_k<<<nb, 1024, 0, stream>>>(cnt_col, col_off, bsc, dinv, n);
    scanB_k<<<1, 1024, 0, stream>>>(bsc, nb);
    scanC_k<<<nb, 1024, 0, stream>>>(col_off, bsc, gs, n, E);
    scatter_k<<<(E / 8 + 255) / 256, 256, 0, stream>>>(ei, E, col_off, rank, cnt_row, csr);

    // encoder + skip (fused): X, skip
    enc_skip_k<<<(n + 255) / 256, 256, 0, stream>>>(x, enc_W, enc_b, W_skip, X, skip, n);

    for (int l = 0; l < NLAYERS; ++l) {
        gather16_k<<<2048, 256, 0, stream>>>(X, csr, col_off, dinv, pre, gs, n);
        update_k<<<(n + 255) / 256, 256, 0, stream>>>(X, pre, skip, conv_W, conv_b, gs, cnt_row, n);
    }

    // decode: out = X @ dec_W^T + dec_b
    dense_small_k<NHID, NCLASS, false, true><<<(n + 255) / 256, 256, 0, stream>>>(X, dec_W, dec_b, (float*)d_out, n);
}

// Round 10
// 991.906 us; speedup vs baseline: 1.0915x; 1.0030x over previous
//
#include <hip/hip_runtime.h>
#include <hip/hip_bf16.h>

#define NFEAT 128
#define NHID  64
#define NCLASS 40
#define NLAYERS 4

// ---------------- CSR build ----------------

// pass 1: rank via returning atomic ONLY (1 atomic/edge)
__global__ __launch_bounds__(256) void count_rank_k(const int* __restrict__ ei, int E,
                             int* __restrict__ cnt_col, int* __restrict__ rank) {
    int t = blockIdx.x * blockDim.x + threadIdx.x;
    int base = t * 4;
    if (base >= E) return;
    if (base + 4 <= E) {
        int4 c4 = *reinterpret_cast<const int4*>(ei + E + base);
        int4 k4;
        k4.x = atomicAdd(&cnt_col[c4.x], 1);
        k4.y = atomicAdd(&cnt_col[c4.y], 1);
        k4.z = atomicAdd(&cnt_col[c4.z], 1);
        k4.w = atomicAdd(&cnt_col[c4.w], 1);
        *reinterpret_cast<int4*>(rank + base) = k4;
    } else {
        for (int e = base; e < E; ++e)
            rank[e] = atomicAdd(&cnt_col[ei[E + e]], 1);
    }
}

// block-level exclusive scan (1024 elems / block), emits block sums; fused dinv
__global__ __launch_bounds__(1024) void scanA_k(const int* __restrict__ cnt, int* __restrict__ off,
                        int* __restrict__ bsum, float* __restrict__ dinv, int n) {
    __shared__ int t[1024];
    int i = blockIdx.x * 1024 + threadIdx.x;
    int x = (i < n) ? cnt[i] : 0;
    if (i < n) dinv[i] = 1.0f / sqrtf((float)(x + 1));   // deg incl. self loop
    t[threadIdx.x] = x;
    __syncthreads();
    for (int d = 1; d < 1024; d <<= 1) {
        int y = (threadIdx.x >= (unsigned)d) ? t[threadIdx.x - d] : 0;
        __syncthreads();
        t[threadIdx.x] += y;
        __syncthreads();
    }
    if (i < n) off[i] = t[threadIdx.x] - x;   // exclusive
    if (threadIdx.x == 1023) bsum[blockIdx.x] = t[1023];
}

__global__ __launch_bounds__(1024) void scanB_k(int* __restrict__ bsum, int nb) {
    __shared__ int t[1024];
    int x = (threadIdx.x < (unsigned)nb) ? bsum[threadIdx.x] : 0;
    t[threadIdx.x] = x;
    __syncthreads();
    for (int d = 1; d < 1024; d <<= 1) {
        int y = (threadIdx.x >= (unsigned)d) ? t[threadIdx.x - d] : 0;
        __syncthreads();
        t[threadIdx.x] += y;
        __syncthreads();
    }
    if (threadIdx.x < (unsigned)nb) bsum[threadIdx.x] = t[threadIdx.x] - x;
}

// finalize offsets; fused gs zero-init
__global__ __launch_bounds__(1024) void scanC_k(int* __restrict__ off, const int* __restrict__ bsum,
                        float* __restrict__ gs, int n, int total) {
    int i = blockIdx.x * 1024 + threadIdx.x;
    if (i < n) {
        off[i] += bsum[blockIdx.x];
        gs[i] = 0.f;
    }
    if (i == 0) off[n] = total;
}

// pass 2: atomic-free slot scatter + out-degree forget-atomics (overlap with stores)
__global__ __launch_bounds__(256) void scatter_k(const int* __restrict__ ei, int E,
                          const int* __restrict__ col_off, const int* __restrict__ rank,
                          int* __restrict__ cnt_row, int* __restrict__ csr) {
    int t = blockIdx.x * blockDim.x + threadIdx.x;
    int base = t * 8;
    if (base >= E) return;
    if (base + 8 <= E) {
        int4 rA = *reinterpret_cast<const int4*>(ei + base);
        int4 rB = *reinterpret_cast<const int4*>(ei + base + 4);
        int4 cA = *reinterpret_cast<const int4*>(ei + E + base);
        int4 cB = *reinterpret_cast<const int4*>(ei + E + base + 4);
        int4 kA = *reinterpret_cast<const int4*>(rank + base);
        int4 kB = *reinterpret_cast<const int4*>(rank + base + 4);
        atomicAdd(&cnt_row[rA.x], 1);
        atomicAdd(&cnt_row[rA.y], 1);
        atomicAdd(&cnt_row[rA.z], 1);
        atomicAdd(&cnt_row[rA.w], 1);
        atomicAdd(&cnt_row[rB.x], 1);
        atomicAdd(&cnt_row[rB.y], 1);
        atomicAdd(&cnt_row[rB.z], 1);
        atomicAdd(&cnt_row[rB.w], 1);
        csr[col_off[cA.x] + kA.x] = rA.x;
        csr[col_off[cA.y] + kA.y] = rA.y;
        csr[col_off[cA.z] + kA.z] = rA.z;
        csr[col_off[cA.w] + kA.w] = rA.w;
        csr[col_off[cB.x] + kB.x] = rB.x;
        csr[col_off[cB.y] + kB.y] = rB.y;
        csr[col_off[cB.z] + kB.z] = rB.z;
        csr[col_off[cB.w] + kB.w] = rB.w;
    } else {
        for (int e = base; e < E; ++e) {
            atomicAdd(&cnt_row[ei[e]], 1);
            csr[col_off[ei[E + e]] + rank[e]] = ei[e];
        }
    }
}

// ---------------- fused encoder + skip projection ----------------
// X = relu(x @ enc_W^T + enc_b); skip = X @ W_skip^T
// mc loop FULLY UNROLLED so xs[]/acc[] indices are compile-time (rule #20:
// runtime-indexed arrays go to scratch). (256,2) -> VGPR cap 256.
__global__ __launch_bounds__(256, 2) void enc_skip_k(const float* __restrict__ A,
                        const float* __restrict__ encW, const float* __restrict__ encb,
                        const float* __restrict__ Wskip,
                        float* __restrict__ X, float* __restrict__ skip, int n) {
    int v = blockIdx.x * blockDim.x + threadIdx.x;
    if (v >= n) return;
    const float4* ap = reinterpret_cast<const float4*>(A + (size_t)v * NFEAT);
    float4* Xp = reinterpret_cast<float4*>(X + (size_t)v * NHID);
    float xs[NHID];
#pragma unroll
    for (int mc = 0; mc < NHID; mc += 32) {
        float acc[32];
#pragma unroll
        for (int m = 0; m < 32; ++m) acc[m] = encb[mc + m];
#pragma unroll 1
        for (int kb = 0; kb < NFEAT / 4; ++kb) {
            float4 a4 = ap[kb];
#pragma unroll
            for (int m = 0; m < 32; ++m) {
                const float* wr = encW + (size_t)(mc + m) * NFEAT + kb * 4;
                acc[m] = fmaf(a4.x, wr[0], acc[m]);
                acc[m] = fmaf(a4.y, wr[1], acc[m]);
                acc[m] = fmaf(a4.z, wr[2], acc[m]);
                acc[m] = fmaf(a4.w, wr[3], acc[m]);
            }
        }
#pragma unroll
        for (int m = 0; m < 32; m += 4) {
            float4 o;
            o.x = fmaxf(acc[m + 0], 0.f);
            o.y = fmaxf(acc[m + 1], 0.f);
            o.z = fmaxf(acc[m + 2], 0.f);
            o.w = fmaxf(acc[m + 3], 0.f);
            xs[mc + m + 0] = o.x; xs[mc + m + 1] = o.y;
            xs[mc + m + 2] = o.z; xs[mc + m + 3] = o.w;
            Xp[(mc + m) >> 2] = o;
        }
    }
    // skip = xs @ Wskip^T
    float4* Sp = reinterpret_cast<float4*>(skip + (size_t)v * NHID);
#pragma unroll 1
    for (int m = 0; m < NHID; m += 4) {
        float s0 = 0.f, s1 = 0.f, s2 = 0.f, s3 = 0.f;
#pragma unroll
        for (int k = 0; k < NHID; ++k) {
            float av = xs[k];
            s0 = fmaf(av, Wskip[(m + 0) * NHID + k], s0);
            s1 = fmaf(av, Wskip[(m + 1) * NHID + k], s1);
            s2 = fmaf(av, Wskip[(m + 2) * NHID + k], s2);
            s3 = fmaf(av, Wskip[(m + 3) * NHID + k], s3);
        }
        float4 o; o.x = s0; o.y = s1; o.z = s2; o.w = s3;
        Sp[m >> 2] = o;
    }
}

// ---------------- dense K=64 (decode): waves_per_eu=4 -> VGPR cap 128 ----------------

template<int K, int M, bool RELU, bool BIAS>
__global__ __launch_bounds__(256, 4) void dense_small_k(const float* __restrict__ A, const float* __restrict__ W,
                              const float* __restrict__ b, float* __restrict__ out, int n) {
    int v = blockIdx.x * blockDim.x + threadIdx.x;
    if (v >= n) return;
    float a[K];
    const float4* ap = reinterpret_cast<const float4*>(A + (size_t)v * K);
#pragma unroll
    for (int k = 0; k < K / 4; ++k) {
        float4 t = ap[k];
        a[4 * k + 0] = t.x; a[4 * k + 1] = t.y; a[4 * k + 2] = t.z; a[4 * k + 3] = t.w;
    }
    float4* op = reinterpret_cast<float4*>(out + (size_t)v * M);
#pragma unroll 1
    for (int m = 0; m < M; m += 4) {
        float acc0 = BIAS ? b[m + 0] : 0.f;
        float acc1 = BIAS ? b[m + 1] : 0.f;
        float acc2 = BIAS ? b[m + 2] : 0.f;
        float acc3 = BIAS ? b[m + 3] : 0.f;
#pragma unroll
        for (int k = 0; k < K; ++k) {
            float av = a[k];
            acc0 = fmaf(av, W[(m + 0) * K + k], acc0);
            acc1 = fmaf(av, W[(m + 1) * K + k], acc1);
            acc2 = fmaf(av, W[(m + 2) * K + k], acc2);
            acc3 = fmaf(av, W[(m + 3) * K + k], acc3);
        }
        if (RELU) {
            acc0 = fmaxf(acc0, 0.f); acc1 = fmaxf(acc1, 0.f);
            acc2 = fmaxf(acc2, 0.f); acc3 = fmaxf(acc3, 0.f);
        }
        float4 o; o.x = acc0; o.y = acc1; o.z = acc2; o.w = acc3;
        op[m >> 2] = o;
    }
}

// ---------------- fused gather (fp32): 16-lane group / node, grid-stride, 8-deep ----------------
// pre[v] = dv*sum(dinv[s]*X[s]) + dv^2*X[v];  gs[s] += ||X[s]-X[v]||^2

#define GLOAD(i) \
    int s##i = csr[e + i]; \
    float w##i = dinv[s##i]; \
    float4 x##i = reinterpret_cast<const float4*>(X + (size_t)s##i * NHID)[sub];

#define GPROC(i) \
    { acc.x = fmaf(w##i, x##i.x, acc.x); acc.y = fmaf(w##i, x##i.y, acc.y); \
      acc.z = fmaf(w##i, x##i.z, acc.z); acc.w = fmaf(w##i, x##i.w, acc.w); \
      float dx = x##i.x - xv.x; p##i = dx * dx; \
      dx = x##i.y - xv.y; p##i = fmaf(dx, dx, p##i); \
      dx = x##i.z - xv.z; p##i = fmaf(dx, dx, p##i); \
      dx = x##i.w - xv.w; p##i = fmaf(dx, dx, p##i); }

__global__ __launch_bounds__(256, 4) void gather16_k(const float* __restrict__ X,
                          const int* __restrict__ csr,
                          const int* __restrict__ col_off, const float* __restrict__ dinv,
                          float* __restrict__ pre, float* __restrict__ gs, int n) {
    int gid = (blockIdx.x * blockDim.x + threadIdx.x) >> 4;
    int ngrp = (gridDim.x * blockDim.x) >> 4;
    int sub = threadIdx.x & 15;

    for (int v = gid; v < n; v += ngrp) {
        float4 xv = reinterpret_cast<const float4*>(X + (size_t)v * NHID)[sub];
        int beg = col_off[v], end = col_off[v + 1];
        float4 acc = make_float4(0.f, 0.f, 0.f, 0.f);
        int e = beg;
        for (; e + 8 <= end; e += 8) {
            GLOAD(0) GLOAD(1) GLOAD(2) GLOAD(3)
            GLOAD(4) GLOAD(5) GLOAD(6) GLOAD(7)
            float p0, p1, p2, p3, p4, p5, p6, p7;
            GPROC(0) GPROC(1) GPROC(2) GPROC(3)
            GPROC(4) GPROC(5) GPROC(6) GPROC(7)
#pragma unroll
            for (int m = 1; m <= 8; m <<= 1) {
                p0 += __shfl_xor(p0, m, 64);
                p1 += __shfl_xor(p1, m, 64);
                p2 += __shfl_xor(p2, m, 64);
                p3 += __shfl_xor(p3, m, 64);
                p4 += __shfl_xor(p4, m, 64);
                p5 += __shfl_xor(p5, m, 64);
                p6 += __shfl_xor(p6, m, 64);
                p7 += __shfl_xor(p7, m, 64);
            }
            if (sub == 0) {
                atomicAdd(&gs[s0], p0);
                atomicAdd(&gs[s1], p1);
                atomicAdd(&gs[s2], p2);
                atomicAdd(&gs[s3], p3);
                atomicAdd(&gs[s4], p4);
                atomicAdd(&gs[s5], p5);
                atomicAdd(&gs[s6], p6);
                atomicAdd(&gs[s7], p7);
            }
        }
        for (; e < end; ++e) {
            GLOAD(0)
            float p0;
            GPROC(0)
#pragma unroll
            for (int m = 1; m <= 8; m <<= 1) p0 += __shfl_xor(p0, m, 64);
            if (sub == 0) atomicAdd(&gs[s0], p0);
        }
        float dv = dinv[v];
        float dv2 = dv * dv;
        float4 o;
        o.x = fmaf(dv, acc.x, dv2 * xv.x);
        o.y = fmaf(dv, acc.y, dv2 * xv.y);
        o.z = fmaf(dv, acc.z, dv2 * xv.z);
        o.w = fmaf(dv, acc.w, dv2 * xv.w);
        reinterpret_cast<float4*>(pre + (size_t)v * NHID)[sub] = o;
    }
}

// ---------------- fused per-layer epilogue: waves_per_eu=4 -> VGPR cap 128 ----------------
// t = relu(pre @ W^T + b); g = tanh(gs/max(outdeg,1));
// X = (X + g*(t + skip)) / (1 + 2g);  gs = 0 for next layer
__global__ __launch_bounds__(256, 4) void update_k(float* __restrict__ X, const float* __restrict__ pre,
                         const float* __restrict__ skip, const float* __restrict__ W,
                         const float* __restrict__ b, float* __restrict__ gs,
                         const int* __restrict__ cnt_row, int n) {
    int v = blockIdx.x * blockDim.x + threadIdx.x;
    if (v >= n) return;
    float a[NHID];
    const float4* ap = reinterpret_cast<const float4*>(pre + (size_t)v * NHID);
#pragma unroll
    for (int k = 0; k < NHID / 4; ++k) {
        float4 t = ap[k];
        a[4 * k + 0] = t.x; a[4 * k + 1] = t.y; a[4 * k + 2] = t.z; a[4 * k + 3] = t.w;
    }
    float gv = tanhf(gs[v] / fmaxf((float)cnt_row[v], 1.f));
    gs[v] = 0.f;
    float inv = 1.0f / (1.0f + 2.0f * gv);

    float4* Xp = reinterpret_cast<float4*>(X + (size_t)v * NHID);
    const float4* Sp = reinterpret_cast<const float4*>(skip + (size_t)v * NHID);
#pragma unroll 1
    for (int m = 0; m < NHID; m += 4) {
        float t0 = b[m + 0], t1 = b[m + 1], t2 = b[m + 2], t3 = b[m + 3];
#pragma unroll
        for (int k = 0; k < NHID; ++k) {
            float av = a[k];
            t0 = fmaf(av, W[(m + 0) * NHID + k], t0);
            t1 = fmaf(av, W[(m + 1) * NHID + k], t1);
            t2 = fmaf(av, W[(m + 2) * NHID + k], t2);
            t3 = fmaf(av, W[(m + 3) * NHID + k], t3);
        }
        t0 = fmaxf(t0, 0.f); t1 = fmaxf(t1, 0.f);
        t2 = fmaxf(t2, 0.f); t3 = fmaxf(t3, 0.f);
        float4 x4 = Xp[m >> 2];
        float4 s4 = Sp[m >> 2];
        float4 o;
        o.x = (x4.x + gv * (t0 + s4.x)) * inv;
        o.y = (x4.y + gv * (t1 + s4.y)) * inv;
        o.z = (x4.z + gv * (t2 + s4.z)) * inv;
        o.w = (x4.w + gv * (t3 + s4.w)) * inv;
        Xp[m >> 2] = o;
    }
}

// ---------------- launch ----------------

extern "C" void kernel_launch(void* const* d_in, const int* in_sizes, int n_in,
                              void* d_out, int out_size, void* d_ws, size_t ws_size,
                              hipStream_t stream) {
    const float* x      = (const float*)d_in[0];
    const int*   ei     = (const int*)  d_in[1];
    const float* enc_W  = (const float*)d_in[2];
    const float* enc_b  = (const float*)d_in[3];
    const float* conv_W = (const float*)d_in[4];
    const float* conv_b = (const float*)d_in[5];
    const float* W_skip = (const float*)d_in[6];
    const float* dec_W  = (const float*)d_in[7];
    const float* dec_b  = (const float*)d_in[8];

    const int n = in_sizes[0] / NFEAT;
    const int E = in_sizes[1] / 2;

    char* ws = (char*)d_ws;
    auto alloc = [&](size_t bytes) {
        char* p = ws;
        ws += (bytes + 255) & ~(size_t)255;
        return p;
    };

    float* X    = (float*)alloc((size_t)n * NHID * 4);
    float* pre  = (float*)alloc((size_t)n * NHID * 4);
    float* skip = (float*)alloc((size_t)n * NHID * 4);
    float* gs   = (float*)alloc((size_t)n * 4);
    float* dinv = (float*)alloc((size_t)n * 4);
    int* cnt_row = (int*)alloc((size_t)n * 4);
    int* cnt_col = (int*)alloc((size_t)n * 4);
    int* col_off = (int*)alloc((size_t)(n + 1) * 4);
    int* rank    = (int*)alloc((size_t)E * 4);
    int* bsc     = (int*)alloc(1024 * 4);
    int* csr     = (int*)alloc((size_t)E * 4);

    hipMemsetAsync(cnt_row, 0, (size_t)n * 4, stream);
    hipMemsetAsync(cnt_col, 0, (size_t)n * 4, stream);

    count_rank_k<<<(E / 4 + 255) / 256, 256, 0, stream>>>(ei, E, cnt_col, rank);

    int nb = (n + 1023) / 1024;
    scanA_k<<<nb, 1024, 0, stream>>>(cnt_col, col_off, bsc, dinv, n);
    scanB_k<<<1, 1024, 0, stream>>>(bsc, nb);
    scanC_k<<<nb, 1024, 0, stream>>>(col_off, bsc, gs, n, E);
    scatter_k<<<(E / 8 + 255) / 256, 256, 0, stream>>>(ei, E, col_off, rank, cnt_row, csr);

    // encoder + skip (fused): X, skip
    enc_skip_k<<<(n + 255) / 256, 256, 0, stream>>>(x, enc_W, enc_b, W_skip, X, skip, n);

    for (int l = 0; l < NLAYERS; ++l) {
        gather16_k<<<2048, 256, 0, stream>>>(X, csr, col_off, dinv, pre, gs, n);
        update_k<<<(n + 255) / 256, 256, 0, stream>>>(X, pre, skip, conv_W, conv_b, gs, cnt_row, n);
    }

    // decode: out = X @ dec_W^T + dec_b
    dense_small_k<NHID, NCLASS, false, true><<<(n + 255) / 256, 256, 0, stream>>>(X, dec_W, dec_b, (float*)d_out, n);
}